// Round 3
// baseline (184.656 us; speedup 1.0000x reference)
//
#include <hip/hip_runtime.h>

// GAE backward scan. B=4096 rows, T=2048 steps.
// R4: 2-deep REGISTER pipeline, persistent blocks, guaranteed residency.
// Theory: R1-R3 all sat at ~2.1-2.3 TB/s because waves hold loads
// outstanding only during their load-wait phase; during the ~2x-longer
// scan/shfl/barrier/store phase a wave has ZERO bytes in flight ->
// machine-wide in-flight reads ~1 MB < the ~3 MB Little's-law minimum
// for 6.3 TB/s. Fix: each block owns 4 rows; row k+1's 8 loads are
// issued into a second register set BEFORE row k's compute, so every
// wave keeps 8 KB of reads in flight through its whole compute phase.
// 1024 blocks x 4 waves = 16 waves/CU resident (launch_bounds caps
// VGPR<=128 so all 4 blocks/CU fit - R3's DMA variant lost residency
// to 112 VGPRs and never tested the pipeline cleanly).
// Barrier = lgkmcnt(0)+s_barrier (no vmcnt drain) with ping-pong LDS
// affines, so in-flight loads survive the per-row barrier.

constexpr float GAMMA = 0.99f;
constexpr float LMBDA = 0.95f;
constexpr float GL    = GAMMA * LMBDA;
constexpr int   T     = 2048;
constexpr int   TPB   = 256;
constexpr int   E     = T / TPB;        // 8 elements per thread
constexpr int   NW    = TPB / 64;       // 4 waves per block
constexpr int   RPB   = 4;              // rows per block (grid = B/RPB)

typedef float f4 __attribute__((ext_vector_type(4)));

struct RowRegs {
    f4   r0, r1;
    int4 t0, t1;
    f4   v0, v1;
    f4   n0, n1;
};

__device__ __forceinline__ RowRegs load_row(const float* __restrict__ rew,
                                            const int*   __restrict__ trm,
                                            const float* __restrict__ val,
                                            const float* __restrict__ nxt,
                                            size_t base)
{
    RowRegs R;
    R.r0 = *(const f4*  )(rew + base);  R.r1 = *(const f4*  )(rew + base + 4);
    R.t0 = *(const int4*)(trm + base);  R.t1 = *(const int4*)(trm + base + 4);
    R.v0 = *(const f4*  )(val + base);  R.v1 = *(const f4*  )(val + base + 4);
    R.n0 = *(const f4*  )(nxt + base);  R.n1 = *(const f4*  )(nxt + base + 4);
    return R;
}

__global__ __launch_bounds__(TPB, 4) void gae_kernel(
    const float* __restrict__ reward,
    const int*   __restrict__ term,
    const float* __restrict__ value,
    const float* __restrict__ next_value,
    float* __restrict__ adv_out,
    float* __restrict__ ret_out)
{
    const int j    = threadIdx.x;
    const int wave = j >> 6;
    const int lane = j & 63;

    __shared__ float sAf[2][NW];
    __shared__ float sBf[2][NW];

    const size_t tbase = (size_t)blockIdx.x * (RPB * T) + (size_t)j * E;

    RowRegs cur = load_row(reward, term, value, next_value, tbase);

    #pragma unroll
    for (int k = 0; k < RPB; ++k) {
        // Issue next row's 8 loads FIRST: they stay in flight through
        // this row's entire scan/barrier/store phase (the compiler's
        // waitcnt for `cur` uses counted vmcnt, leaving these pending).
        RowRegs nxt;
        if (k + 1 < RPB)
            nxt = load_row(reward, term, value, next_value,
                           tbase + (size_t)(k + 1) * T);

        // Unpack current row; fold into delta/c immediately.
        const float r [E] = {cur.r0[0], cur.r0[1], cur.r0[2], cur.r0[3],
                             cur.r1[0], cur.r1[1], cur.r1[2], cur.r1[3]};
        const float nd[E] = {1.f - (float)cur.t0.x, 1.f - (float)cur.t0.y,
                             1.f - (float)cur.t0.z, 1.f - (float)cur.t0.w,
                             1.f - (float)cur.t1.x, 1.f - (float)cur.t1.y,
                             1.f - (float)cur.t1.z, 1.f - (float)cur.t1.w};
        const float v [E] = {cur.v0[0], cur.v0[1], cur.v0[2], cur.v0[3],
                             cur.v1[0], cur.v1[1], cur.v1[2], cur.v1[3]};
        const float nx[E] = {cur.n0[0], cur.n0[1], cur.n0[2], cur.n0[3],
                             cur.n1[0], cur.n1[1], cur.n1[2], cur.n1[3]};

        // Intra-thread backward scan, zero carry.
        float loc[E], P[E];
        {
            float g = 0.f, p = 1.f;
            #pragma unroll
            for (int t = E - 1; t >= 0; --t) {
                const float c     = GL * nd[t];
                const float delta = fmaf(GAMMA * nx[t], nd[t], r[t]) - v[t];
                g = fmaf(c, g, delta);
                p *= c;
                loc[t] = g;
                P[t]   = p;
            }
        }

        // Per-wave inclusive suffix-composition scan of (A,B)=(loc[0],P[0]).
        float A = loc[0], Bc = P[0];
        #pragma unroll
        for (int off = 1; off < 64; off <<= 1) {
            const float a2 = __shfl_down(A,  off, 64);
            const float b2 = __shfl_down(Bc, off, 64);
            if (lane + off < 64) {
                A  = fmaf(Bc, a2, A);
                Bc *= b2;
            }
        }

        // Publish wave affine (ping-pong by row parity: WAR between
        // iteration k's reads and k+2's writes is separated by k+1's
        // barrier, so ONE barrier per row suffices).
        const int pb = k & 1;
        if (lane == 0) { sAf[pb][wave] = A; sBf[pb][wave] = Bc; }

        // Exclusive suffix within the wave; lane 63 = identity.
        float eA = __shfl_down(A,  1, 64);
        float eB = __shfl_down(Bc, 1, 64);
        if (lane == 63) { eA = 0.f; eB = 1.f; }

        // Non-draining barrier: only LDS ops must land; next-row global
        // loads stay in flight (__syncthreads would drain vmcnt(0)).
        asm volatile("s_waitcnt lgkmcnt(0)" ::: "memory");
        __builtin_amdgcn_s_barrier();
        asm volatile("" ::: "memory");

        // Carry entering this wave = composition of wave-affines right of it.
        float wcarry = 0.f;
        #pragma unroll
        for (int w = NW - 1; w > 0; --w) {
            if (w > wave) wcarry = fmaf(sBf[pb][w], wcarry, sAf[pb][w]);
        }

        // Carry entering this thread's chunk.
        const float gin = fmaf(eB, wcarry, eA);

        f4 a0, a1, q0, q1;
        #pragma unroll
        for (int t = 0; t < 4; ++t) {
            const float aa = fmaf(P[t], gin, loc[t]);
            const float ab = fmaf(P[t + 4], gin, loc[t + 4]);
            a0[t] = aa;  q0[t] = aa + v[t];
            a1[t] = ab;  q1[t] = ab + v[t + 4];
        }
        const size_t gb = tbase + (size_t)k * T;
        __builtin_nontemporal_store(a0, (f4*)(adv_out + gb));
        __builtin_nontemporal_store(a1, (f4*)(adv_out + gb + 4));
        __builtin_nontemporal_store(q0, (f4*)(ret_out + gb));
        __builtin_nontemporal_store(q1, (f4*)(ret_out + gb + 4));

        if (k + 1 < RPB) cur = nxt;
    }
}

extern "C" void kernel_launch(void* const* d_in, const int* in_sizes, int n_in,
                              void* d_out, int out_size, void* d_ws, size_t ws_size,
                              hipStream_t stream) {
    const float* reward     = (const float*)d_in[0];
    const int*   term       = (const int*  )d_in[1];
    const float* value      = (const float*)d_in[2];
    const float* next_value = (const float*)d_in[3];

    const int BT = in_sizes[0];
    const int B  = BT / T;

    float* adv = (float*)d_out;
    float* ret = adv + BT;

    gae_kernel<<<B / RPB, TPB, 0, stream>>>(reward, term, value, next_value, adv, ret);
}